// Round 13
// baseline (295.546 us; speedup 1.0000x reference)
//
#include <hip/hip_runtime.h>

#define HH 128
#define EPS 1e-5f
#define NBMAX 256     // max buckets (N < 65536 assumed: node ids fit ushort)
#define SCAP 40       // scatter LDS queue capacity per bucket
#define FCAP 12288    // finalize LDS edge capacity per bucket
#define MGRID 256     // mega-prologue grid (co-resident: <= 256 CUs)

typedef __bf16 bf16x8 __attribute__((ext_vector_type(8)));
typedef float f32x4 __attribute__((ext_vector_type(4)));
typedef float f32x2 __attribute__((ext_vector_type(2)));

__device__ __forceinline__ unsigned f2bf(float f) {
    unsigned u = __builtin_bit_cast(unsigned, f);
    return (u + 0x7FFFu + ((u >> 16) & 1u)) >> 16;   // RNE
}
__device__ __forceinline__ float bflo(unsigned w) { return __builtin_bit_cast(float, w << 16); }
__device__ __forceinline__ float bfhi(unsigned w) { return __builtin_bit_cast(float, w & 0xFFFF0000u); }

// pack 4 f32 -> 4 fp8 e4m3 (one uint); HW cvt (OCP on gfx950)
__device__ __forceinline__ unsigned pack_fp8x4(float f0, float f1, float f2, float f3) {
    unsigned r = 0;
    r = __builtin_amdgcn_cvt_pk_fp8_f32(f0, f1, r, false);   // bytes 0,1
    r = __builtin_amdgcn_cvt_pk_fp8_f32(f2, f3, r, true);    // bytes 2,3
    return r;
}

__device__ __forceinline__ void gload_lds16(const void* g, void* l) {
    __builtin_amdgcn_global_load_lds(
        (const __attribute__((address_space(1))) unsigned int*)g,
        (__attribute__((address_space(3))) unsigned int*)l,
        16, 0, 0);
}

// device-scope grid barrier (all co-resident blocks); threadfence-release on arrive
__device__ __forceinline__ void grid_barrier(unsigned* ctr, unsigned nb) {
    __syncthreads();
    if (threadIdx.x == 0) {
        __threadfence();
        __hip_atomic_fetch_add(ctr, 1u, __ATOMIC_ACQ_REL, __HIP_MEMORY_SCOPE_AGENT);
        while (__hip_atomic_load(ctr, __ATOMIC_ACQUIRE, __HIP_MEMORY_SCOPE_AGENT) < nb)
            __builtin_amdgcn_s_sleep(8);
    }
    __syncthreads();
}

__device__ __forceinline__ int aload(const int* p) {
    return __hip_atomic_load((int*)p, __ATOMIC_RELAXED, __HIP_MEMORY_SCOPE_AGENT);
}

// ---------------- tiny zero (bcnt + stats + barrier counters) ----------------
__global__ void zero_small_kernel(int* __restrict__ bcnt, float* __restrict__ stats3,
                                  unsigned* __restrict__ bar) {
    const int t = threadIdx.x;
    bcnt[t] = 0;
    stats3[t] = 0.f; stats3[256 + t] = 0.f; stats3[512 + t] = 0.f;
    if (t < 8) bar[t] = 0u;
}

// ---------------- mega prologue: convert + CSR build in ONE kernel ----------------
// P0: convert W->bf16, x->bf16+fp8 (zero-padded); LDS-private bucket hist -> bcnt.
// P1: block 0 scans bcnt -> boff/gpos.  P2: LDS-staged scatter of (dst<<16|src).
// P3: per-bucket finalize -> row_ptr/invdeg/edge_csr.  Grid barriers between phases.
__global__ __launch_bounds__(256) void mega_prologue_kernel(
    const float* __restrict__ x, const float* __restrict__ Wl, const float* __restrict__ Wr,
    const int* __restrict__ src, const int* __restrict__ dst,
    ushort* __restrict__ xb, unsigned* __restrict__ xq, ushort* __restrict__ Wb,
    int* __restrict__ bcnt, int* __restrict__ boff, int* __restrict__ gpos,
    unsigned* __restrict__ packed, int* __restrict__ row_ptr,
    float* __restrict__ invdeg, ushort* __restrict__ edge_csr,
    unsigned* __restrict__ bar,
    int n4, int m4, int wtotal, int N, int E, int NB)
{
    __shared__ char smraw[NBMAX * SCAP * 4 + NBMAX * 4];   // 41 KB, reused per phase
    const int t = threadIdx.x;
    const int b = blockIdx.x;
    const int gt = b * 256 + t;
    const int gstride = MGRID * 256;

    // ---- P0: LDS hist + flush; convert W + x ----
    {
        int* h0 = (int*)smraw;
        h0[t] = 0;
        __syncthreads();
        for (int e = gt; e < E; e += gstride) atomicAdd(&h0[dst[e] >> 8], 1);
        __syncthreads();
        if (h0[t]) atomicAdd(&bcnt[t], h0[t]);
    }
    for (int i = gt; i < wtotal; i += gstride) {
        int l = i / (HH * 256);
        int rem = i - l * (HH * 256);
        int col = rem >> 8;
        int k = rem & 255;
        float v = (k < HH) ? Wl[(size_t)l * HH * HH + col * HH + k]
                           : Wr[(size_t)l * HH * HH + col * HH + (k - HH)];
        Wb[i] = (ushort)f2bf(v);
    }
    for (int i = gt; i < m4; i += gstride) {
        uint2 o = make_uint2(0u, 0u);
        unsigned qv = 0u;
        if (i < n4) {
            float4 v = ((const float4*)x)[i];
            o.x = f2bf(v.x) | (f2bf(v.y) << 16);
            o.y = f2bf(v.z) | (f2bf(v.w) << 16);
            qv = pack_fp8x4(v.x, v.y, v.z, v.w);
        }
        ((uint2*)xb)[i] = o;
        xq[i] = qv;
    }

    grid_barrier(bar + 0, MGRID);

    // ---- P1: exclusive scan of bucket counts (block 0) ----
    if (b == 0) {
        int* s = (int*)smraw;
        s[t] = (t < NB) ? aload(&bcnt[t]) : 0;
        __syncthreads();
        for (int off = 1; off < 256; off <<= 1) {
            int u = (t >= off) ? s[t - off] : 0;
            __syncthreads();
            s[t] += u;
            __syncthreads();
        }
        int excl = (t == 0) ? 0 : s[t - 1];
        if (t < NB) { boff[t] = excl; gpos[t] = excl; }
        if (t == 0) boff[NB] = E;
    }

    grid_barrier(bar + 1, MGRID);

    // ---- P2: LDS-staged scatter ----
    {
        unsigned (*q)[SCAP] = (unsigned (*)[SCAP])smraw;
        int* qc = (int*)(smraw + NBMAX * SCAP * 4);
        qc[t] = 0;
        __syncthreads();
        const int ebeg = (int)((long)b * E / MGRID);
        const int eend = (int)((long)(b + 1) * E / MGRID);
        for (int base = ebeg; base < eend; base += 256) {
            int e = base + t;
            if (e < eend) {
                int d = dst[e];
                unsigned pk = ((unsigned)d << 16) | (unsigned)src[e];
                int bk = d >> 8;
                int slot = atomicAdd(&qc[bk], 1);
                if (slot < SCAP) q[bk][slot] = pk;
                else { int p = atomicAdd(&gpos[bk], 1); packed[p] = pk; }
            }
            __syncthreads();
            int c = qc[t]; if (c > SCAP) c = SCAP;
            if (c >= 32) {
                int p = atomicAdd(&gpos[t], 32);
                for (int i = 0; i < 32; ++i) packed[p + i] = q[t][i];
                for (int i = 32; i < c; ++i) q[t][i - 32] = q[t][i];
                qc[t] = c - 32;
            } else {
                qc[t] = c;
            }
            __syncthreads();
        }
        int c = qc[t]; if (c > SCAP) c = SCAP;
        if (c > 0) {
            int p = atomicAdd(&gpos[t], c);
            for (int i = 0; i < c; ++i) packed[p + i] = q[t][i];
        }
    }

    grid_barrier(bar + 2, MGRID);

    // ---- P3: per-bucket finalize (blocks < NB) ----
    if (b < NB) {
        int* hist = (int*)smraw;
        int* posq = hist + 256;
        ushort* outq = (ushort*)(posq + 256);
        const int beg = aload(&boff[b]);
        const int end = aload(&boff[b + 1]);
        const int n = end - beg;
        hist[t] = 0;
        __syncthreads();
        for (int i = beg + t; i < end; i += 256)
            atomicAdd(&hist[(packed[i] >> 16) & 255], 1);
        __syncthreads();
        const int c = hist[t];
        for (int off = 1; off < 256; off <<= 1) {
            int u = (t >= off) ? hist[t - off] : 0;
            __syncthreads();
            hist[t] += u;
            __syncthreads();
        }
        const int excl = hist[t] - c;
        const int node = (b << 8) + t;
        if (node < N) {
            row_ptr[node] = beg + excl;
            invdeg[node] = 1.0f / fmaxf((float)c, 1.0f);
        }
        if (b == 0 && t == 0) row_ptr[N] = E;
        posq[t] = excl;
        __syncthreads();
        if (n <= FCAP) {
            for (int i = beg + t; i < end; i += 256) {
                unsigned pk = packed[i];
                int p = atomicAdd(&posq[(pk >> 16) & 255], 1);
                outq[p] = (ushort)(pk & 0xFFFFu);
            }
            __syncthreads();
            for (int i = t; i < n; i += 256) edge_csr[beg + i] = outq[i];
        } else {
            for (int i = beg + t; i < end; i += 256) {
                unsigned pk = packed[i];
                int p = atomicAdd(&posq[(pk >> 16) & 255], 1);
                edge_csr[beg + p] = (ushort)(pk & 0xFFFFu);
            }
        }
    }
}

// ---------------- gather (fp8 in, f32 accum, bf16 out), unroll-4 ----------------
__global__ __launch_bounds__(256) void gather_kernel(
    const unsigned* __restrict__ xq, const int* __restrict__ row_ptr,
    const ushort* __restrict__ edge_csr, const float* __restrict__ invdeg,
    ushort* __restrict__ aggb, int N)
{
    const int node = blockIdx.x * 16 + (threadIdx.x >> 4);
    const int l16 = threadIdx.x & 15;
    float a0=0,a1=0,a2=0,a3=0,a4=0,a5=0,a6=0,a7=0;
    float id = 0.f;
    if (node < N) {
        const int beg = row_ptr[node], end = row_ptr[node + 1];
        id = invdeg[node];
        int e = beg;
        for (; e + 3 < end; e += 4) {
            int s0 = edge_csr[e], s1 = edge_csr[e + 1];
            int s2 = edge_csr[e + 2], s3 = edge_csr[e + 3];
            uint2 v0 = *(const uint2*)(xq + (size_t)s0 * 32 + l16 * 2);
            uint2 v1 = *(const uint2*)(xq + (size_t)s1 * 32 + l16 * 2);
            uint2 v2 = *(const uint2*)(xq + (size_t)s2 * 32 + l16 * 2);
            uint2 v3 = *(const uint2*)(xq + (size_t)s3 * 32 + l16 * 2);
            f32x2 p;
            p = __builtin_amdgcn_cvt_pk_f32_fp8(v0.x, false); a0 += p.x; a1 += p.y;
            p = __builtin_amdgcn_cvt_pk_f32_fp8(v0.x, true);  a2 += p.x; a3 += p.y;
            p = __builtin_amdgcn_cvt_pk_f32_fp8(v0.y, false); a4 += p.x; a5 += p.y;
            p = __builtin_amdgcn_cvt_pk_f32_fp8(v0.y, true);  a6 += p.x; a7 += p.y;
            p = __builtin_amdgcn_cvt_pk_f32_fp8(v1.x, false); a0 += p.x; a1 += p.y;
            p = __builtin_amdgcn_cvt_pk_f32_fp8(v1.x, true);  a2 += p.x; a3 += p.y;
            p = __builtin_amdgcn_cvt_pk_f32_fp8(v1.y, false); a4 += p.x; a5 += p.y;
            p = __builtin_amdgcn_cvt_pk_f32_fp8(v1.y, true);  a6 += p.x; a7 += p.y;
            p = __builtin_amdgcn_cvt_pk_f32_fp8(v2.x, false); a0 += p.x; a1 += p.y;
            p = __builtin_amdgcn_cvt_pk_f32_fp8(v2.x, true);  a2 += p.x; a3 += p.y;
            p = __builtin_amdgcn_cvt_pk_f32_fp8(v2.y, false); a4 += p.x; a5 += p.y;
            p = __builtin_amdgcn_cvt_pk_f32_fp8(v2.y, true);  a6 += p.x; a7 += p.y;
            p = __builtin_amdgcn_cvt_pk_f32_fp8(v3.x, false); a0 += p.x; a1 += p.y;
            p = __builtin_amdgcn_cvt_pk_f32_fp8(v3.x, true);  a2 += p.x; a3 += p.y;
            p = __builtin_amdgcn_cvt_pk_f32_fp8(v3.y, false); a4 += p.x; a5 += p.y;
            p = __builtin_amdgcn_cvt_pk_f32_fp8(v3.y, true);  a6 += p.x; a7 += p.y;
        }
        for (; e < end; ++e) {
            int s0 = edge_csr[e];
            uint2 v0 = *(const uint2*)(xq + (size_t)s0 * 32 + l16 * 2);
            f32x2 p;
            p = __builtin_amdgcn_cvt_pk_f32_fp8(v0.x, false); a0 += p.x; a1 += p.y;
            p = __builtin_amdgcn_cvt_pk_f32_fp8(v0.x, true);  a2 += p.x; a3 += p.y;
            p = __builtin_amdgcn_cvt_pk_f32_fp8(v0.y, false); a4 += p.x; a5 += p.y;
            p = __builtin_amdgcn_cvt_pk_f32_fp8(v0.y, true);  a6 += p.x; a7 += p.y;
        }
    }
    uint4 o;
    o.x = f2bf(a0 * id) | (f2bf(a1 * id) << 16);
    o.y = f2bf(a2 * id) | (f2bf(a3 * id) << 16);
    o.z = f2bf(a4 * id) | (f2bf(a5 * id) << 16);
    o.w = f2bf(a6 * id) | (f2bf(a7 * id) << 16);
    *(uint4*)(aggb + (size_t)node * HH + l16 * 8) = o;
}

// ---------------- fused GEMM + BN + ReLU + residual (grid-barrier, h stays in regs) ---------
__global__ __launch_bounds__(512) void fused_layer_kernel(
    const ushort* __restrict__ aggb, ushort* __restrict__ xb,
    const ushort* __restrict__ Wb, const float* __restrict__ bl,
    const float* __restrict__ gamma, const float* __restrict__ beta,
    float* __restrict__ stats, unsigned* __restrict__ bar,
    unsigned* __restrict__ xq, float* __restrict__ outf,
    float invN, int nblocks, int N, int residual, int final_layer)
{
    extern __shared__ ushort As[];          // 256 rows x 256 k bf16 = 128 KB; reused as C-tile
    __shared__ float s_sum[128];
    __shared__ float s_sum2[128];

    const int tid = threadIdx.x;
    const int lane = tid & 63;
    const int wave = tid >> 6;              // 0..7
    const int m0 = blockIdx.x * 256;
    const int l15 = lane & 15;
    const int lg = lane >> 4;
    const int col = wave * 16 + l15;        // this lane's output column

    // stage A: 8192 16B-chunks (XOR swizzle on global source, linear LDS dest)
#pragma unroll
    for (int i = 0; i < 16; ++i) {
        const int cb = (i * 8 + wave) * 64;          // wave-uniform chunk base
        const int L = cb + lane;
        const int r = L >> 5;                        // row 0..255
        const int c = L & 31;
        const int cs = (c & 0x18) | ((c & 7) ^ (r & 7));
        const ushort* gsrc = (cs < 16)
            ? (aggb + (size_t)(m0 + r) * HH + cs * 8)
            : (xb   + (size_t)(m0 + r) * HH + (cs - 16) * 8);
        gload_lds16(gsrc, &As[(size_t)cb * 8]);
    }

    // B preload: 8 k-steps for this wave's 16-col strip (32 VGPRs)
    bf16x8 bfr[8];
#pragma unroll
    for (int s = 0; s < 8; ++s)
        bfr[s] = *(const bf16x8*)(Wb + (size_t)col * 256 + s * 32 + lg * 8);

    if (tid < 128) { s_sum[tid] = 0.f; s_sum2[tid] = 0.f; }

    f32x4 acc[16];
#pragma unroll
    for (int rt = 0; rt < 16; ++rt) acc[rt] = (f32x4){0.f, 0.f, 0.f, 0.f};

    __syncthreads();   // drains vmcnt (global_load_lds); also publishes s_sum init

#pragma unroll
    for (int s = 0; s < 8; ++s) {
#pragma unroll
        for (int rt = 0; rt < 16; ++rt) {
            const int r = rt * 16 + l15;
            const int g = s * 4 + lg;
            const int c = (g & 0x18) | ((g & 7) ^ (r & 7));
            bf16x8 a = *(const bf16x8*)&As[r * 256 + c * 8];
            acc[rt] = __builtin_amdgcn_mfma_f32_16x16x32_bf16(a, bfr[s], acc[rt], 0, 0, 0);
        }
    }

    // stats (h = acc + bias, rows < N only)
    const float bias = bl[col];
    float s1 = 0.f, s2 = 0.f;
#pragma unroll
    for (int rt = 0; rt < 16; ++rt) {
#pragma unroll
        for (int r = 0; r < 4; ++r) {
            const int row = rt * 16 + lg * 4 + r;
            if (m0 + row < N) {
                float v = acc[rt][r] + bias;
                s1 += v; s2 += v * v;
            }
        }
    }
    atomicAdd(&s_sum[col], s1);
    atomicAdd(&s_sum2[col], s2);
    __syncthreads();
    if (tid < 128) {
        atomicAdd(&stats[tid], s_sum[tid]);
        atomicAdd(&stats[128 + tid], s_sum2[tid]);
    }
    // grid barrier
    if (tid == 0) {
        __threadfence();
        __hip_atomic_fetch_add(bar, 1u, __ATOMIC_ACQ_REL, __HIP_MEMORY_SCOPE_AGENT);
        while (__hip_atomic_load(bar, __ATOMIC_ACQUIRE, __HIP_MEMORY_SCOPE_AGENT) < (unsigned)nblocks)
            __builtin_amdgcn_s_sleep(8);
    }
    __syncthreads();

    // BN coefficients (atomic loads bypass stale per-XCD cache copies)
    const float sA = __hip_atomic_load(&stats[col], __ATOMIC_RELAXED, __HIP_MEMORY_SCOPE_AGENT);
    const float sB = __hip_atomic_load(&stats[128 + col], __ATOMIC_RELAXED, __HIP_MEMORY_SCOPE_AGENT);
    const float mean = sA * invN;
    const float var = sB * invN - mean * mean;
    const float aa = gamma[col] * rsqrtf(var + EPS);
    const float bb = beta[col] - mean * aa;

    // write relu(bn(h)) into LDS C-tile
    ushort* Cs = As;   // [256][136] ushort
#pragma unroll
    for (int rt = 0; rt < 16; ++rt) {
#pragma unroll
        for (int r = 0; r < 4; ++r) {
            const int row = rt * 16 + lg * 4 + r;
            float v = acc[rt][r] + bias;
            float o = fmaxf(fmaf(v, aa, bb), 0.f);
            Cs[row * 136 + col] = (ushort)f2bf(o);
        }
    }
    __syncthreads();

    // coalesced copy-out: + residual, write xb (bf16) + xq (fp8) or final f32 out
#pragma unroll
    for (int i = 0; i < 8; ++i) {
        const int ch = tid + i * 512;
        const int row = ch >> 4;
        const int q = ch & 15;
        const int grow = m0 + row;
        if (grow < N) {
            uint4 v = *(const uint4*)&Cs[row * 136 + q * 8];
            float o0 = bflo(v.x), o1 = bfhi(v.x);
            float o2 = bflo(v.y), o3 = bfhi(v.y);
            float o4 = bflo(v.z), o5 = bfhi(v.z);
            float o6 = bflo(v.w), o7 = bfhi(v.w);
            if (residual) {
                uint4 xw = *(const uint4*)(xb + (size_t)grow * HH + q * 8);
                o0 += bflo(xw.x); o1 += bfhi(xw.x);
                o2 += bflo(xw.y); o3 += bfhi(xw.y);
                o4 += bflo(xw.z); o5 += bfhi(xw.z);
                o6 += bflo(xw.w); o7 += bfhi(xw.w);
            }
            if (final_layer) {
                float* op = outf + (size_t)grow * HH + q * 8;
                *(float4*)op = make_float4(o0, o1, o2, o3);
                *(float4*)(op + 4) = make_float4(o4, o5, o6, o7);
            } else {
                uint4 ob;
                ob.x = f2bf(o0) | (f2bf(o1) << 16);
                ob.y = f2bf(o2) | (f2bf(o3) << 16);
                ob.z = f2bf(o4) | (f2bf(o5) << 16);
                ob.w = f2bf(o6) | (f2bf(o7) << 16);
                *(uint4*)(xb + (size_t)grow * HH + q * 8) = ob;
                uint2 qb;
                qb.x = pack_fp8x4(o0, o1, o2, o3);
                qb.y = pack_fp8x4(o4, o5, o6, o7);
                *(uint2*)(xq + (size_t)grow * 32 + q * 2) = qb;
            }
        }
    }
}

extern "C" void kernel_launch(void* const* d_in, const int* in_sizes, int n_in,
                              void* d_out, int out_size, void* d_ws, size_t ws_size,
                              hipStream_t stream) {
    const float* x     = (const float*)d_in[0];
    const int*   ei    = (const int*)d_in[1];
    const float* Wl    = (const float*)d_in[2];
    const float* bl    = (const float*)d_in[3];
    const float* Wr    = (const float*)d_in[4];
    const float* gamma = (const float*)d_in[5];
    const float* beta  = (const float*)d_in[6];
    float* out = (float*)d_out;

    const int N = in_sizes[0] / HH;           // 50000 (< 65536: ushort node ids)
    const int E = in_sizes[1] / 2;
    const int MP = ((N + 255) / 256) * 256;   // 256-row tiles
    const int NB = (N + 255) >> 8;
    const int* src = ei;
    const int* dst = ei + E;

    char* p = (char*)d_ws;
    ushort* aggb    = (ushort*)p; p += (size_t)MP * HH * 2;
    ushort* xb      = (ushort*)p; p += (size_t)MP * HH * 2;
    unsigned* xq    = (unsigned*)p; p += (size_t)MP * 32 * 4; // fp8 shadow of x (128 B/row)
    ushort* Wb      = (ushort*)p; p += (size_t)3 * HH * 256 * 2;
    float* invdeg   = (float*)p;  p += (size_t)N * 4;
    float* stats3   = (float*)p;  p += 768 * 4;
    unsigned* bar   = (unsigned*)p; p += 16 * 4;             // [0..2] mega phases, [3..5] layers
    int* row_ptr    = (int*)p;    p += (size_t)(N + 4) * 4;
    int* bcnt       = (int*)p;    p += NBMAX * 4;
    int* boff       = (int*)p;    p += (NBMAX + 1) * 4;
    int* gpos       = (int*)p;    p += NBMAX * 4;
    unsigned* packed = (unsigned*)p; p += (size_t)E * 4;
    ushort* edge_csr = (ushort*)p;  p += (size_t)((E + 7) & ~7) * 2;

    // allow 128 KB dynamic LDS for the fused kernel (gfx950 LDS/CU = 160 KB)
    hipFuncSetAttribute((const void*)fused_layer_kernel,
                        hipFuncAttributeMaxDynamicSharedMemorySize, 131072);

    const int wtotal = 3 * HH * 256;
    const int n4 = N * (HH / 4);
    const int m4 = MP * (HH / 4);

    // ---- prologue: zero + mega (convert + CSR build) ----
    zero_small_kernel<<<1, 256, 0, stream>>>(bcnt, stats3, bar);
    mega_prologue_kernel<<<MGRID, 256, 0, stream>>>(
        x, Wl, Wr, src, dst, xb, xq, Wb,
        bcnt, boff, gpos, packed, row_ptr, invdeg, edge_csr,
        bar, n4, m4, wtotal, N, E, NB);

    const int gather_blocks = MP / 16;
    const int fused_blocks = MP / 256;        // 196 <= 256 -> co-resident (1 block/CU by LDS)

    for (int layer = 0; layer < 3; ++layer) {
        gather_kernel<<<gather_blocks, 256, 0, stream>>>(
            xq, row_ptr, edge_csr, invdeg, aggb, N);

        fused_layer_kernel<<<fused_blocks, 512, 131072, stream>>>(
            aggb, xb, Wb + (size_t)layer * HH * 256, bl + (size_t)layer * HH,
            gamma + (size_t)layer * HH, beta + (size_t)layer * HH,
            stats3 + layer * 256, bar + 3 + layer,
            xq, out, 1.0f / (float)N, fused_blocks, N,
            layer > 0 ? 1 : 0, layer == 2 ? 1 : 0);
    }
}

// Round 14
// 277.353 us; speedup vs baseline: 1.0656x; 1.0656x over previous
//
#include <hip/hip_runtime.h>

#define HH 128
#define EPS 1e-5f
#define NBMAX 256     // max buckets (N < 65536 assumed: node ids fit ushort)
#define SCAP 40       // scatter LDS queue capacity per bucket
#define FCAP 12288    // finalize LDS edge capacity per bucket

typedef __bf16 bf16x8 __attribute__((ext_vector_type(8)));
typedef float f32x4 __attribute__((ext_vector_type(4)));
typedef float f32x2 __attribute__((ext_vector_type(2)));

__device__ __forceinline__ unsigned f2bf(float f) {
    unsigned u = __builtin_bit_cast(unsigned, f);
    return (u + 0x7FFFu + ((u >> 16) & 1u)) >> 16;   // RNE
}
__device__ __forceinline__ float bflo(unsigned w) { return __builtin_bit_cast(float, w << 16); }
__device__ __forceinline__ float bfhi(unsigned w) { return __builtin_bit_cast(float, w & 0xFFFF0000u); }

// pack 4 f32 -> 4 fp8 e4m3 (one uint); HW cvt (OCP on gfx950)
__device__ __forceinline__ unsigned pack_fp8x4(float f0, float f1, float f2, float f3) {
    unsigned r = 0;
    r = __builtin_amdgcn_cvt_pk_fp8_f32(f0, f1, r, false);   // bytes 0,1
    r = __builtin_amdgcn_cvt_pk_fp8_f32(f2, f3, r, true);    // bytes 2,3
    return r;
}

__device__ __forceinline__ void gload_lds16(const void* g, void* l) {
    __builtin_amdgcn_global_load_lds(
        (const __attribute__((address_space(1))) unsigned int*)g,
        (__attribute__((address_space(3))) unsigned int*)l,
        16, 0, 0);
}

// ---------------- tiny zero (bcnt + stats + barrier counters) ----------------
__global__ void zero_small_kernel(int* __restrict__ bcnt, float* __restrict__ stats3,
                                  unsigned* __restrict__ bar) {
    const int t = threadIdx.x;
    bcnt[t] = 0;
    stats3[t] = 0.f; stats3[256 + t] = 0.f; stats3[512 + t] = 0.f;
    if (t < 8) bar[t] = 0u;
}

// ---------------- CSR build (bucketed, once) ----------------
__global__ __launch_bounds__(256) void bucket_hist_kernel(const int* __restrict__ dst,
                                                          int* __restrict__ bcnt, int E) {
    __shared__ int h[NBMAX];
    const int t = threadIdx.x;
    h[t] = 0;
    __syncthreads();
    for (int e = blockIdx.x * 256 + t; e < E; e += gridDim.x * 256)
        atomicAdd(&h[dst[e] >> 8], 1);
    __syncthreads();
    if (h[t]) atomicAdd(&bcnt[t], h[t]);
}

__global__ __launch_bounds__(256) void bucket_scan_kernel(const int* __restrict__ bcnt,
                                                          int* __restrict__ boff,
                                                          int* __restrict__ gpos, int NB, int E) {
    __shared__ int s[NBMAX];
    const int t = threadIdx.x;
    s[t] = (t < NB) ? bcnt[t] : 0;
    __syncthreads();
    for (int off = 1; off < 256; off <<= 1) {
        int u = (t >= off) ? s[t - off] : 0;
        __syncthreads();
        s[t] += u;
        __syncthreads();
    }
    int excl = (t == 0) ? 0 : s[t - 1];
    if (t < NB) { boff[t] = excl; gpos[t] = excl; }
    if (t == 0) boff[NB] = E;
}

__global__ __launch_bounds__(256) void bucket_scatter_kernel(
    const int* __restrict__ src, const int* __restrict__ dst,
    int* __restrict__ gpos, unsigned* __restrict__ packed, int E, int GRID)
{
    __shared__ unsigned q[NBMAX][SCAP];
    __shared__ int qc[NBMAX];
    const int t = threadIdx.x;
    const int b = blockIdx.x;
    qc[t] = 0;
    __syncthreads();
    const int ebeg = (int)((long)b * E / GRID);
    const int eend = (int)((long)(b + 1) * E / GRID);
    for (int base = ebeg; base < eend; base += 256) {
        int e = base + t;
        if (e < eend) {
            int d = dst[e];
            unsigned pk = ((unsigned)d << 16) | (unsigned)src[e];
            int bk = d >> 8;
            int slot = atomicAdd(&qc[bk], 1);
            if (slot < SCAP) q[bk][slot] = pk;
            else { int p = atomicAdd(&gpos[bk], 1); packed[p] = pk; }
        }
        __syncthreads();
        int c = qc[t]; if (c > SCAP) c = SCAP;
        if (c >= 32) {
            int p = atomicAdd(&gpos[t], 32);
            for (int i = 0; i < 32; ++i) packed[p + i] = q[t][i];
            for (int i = 32; i < c; ++i) q[t][i - 32] = q[t][i];
            qc[t] = c - 32;
        } else {
            qc[t] = c;
        }
        __syncthreads();
    }
    int c = qc[t]; if (c > SCAP) c = SCAP;
    if (c > 0) {
        int p = atomicAdd(&gpos[t], c);
        for (int i = 0; i < c; ++i) packed[p + i] = q[t][i];
    }
}

__global__ __launch_bounds__(256) void bucket_finalize_kernel(
    const unsigned* __restrict__ packed, const int* __restrict__ boff,
    int* __restrict__ row_ptr, float* __restrict__ invdeg,
    ushort* __restrict__ edge_csr, int N, int E)
{
    __shared__ int hist[256];
    __shared__ int posq[256];
    __shared__ ushort outq[FCAP];
    const int b = blockIdx.x, t = threadIdx.x;
    const int beg = boff[b], end = boff[b + 1], n = end - beg;
    hist[t] = 0;
    __syncthreads();
    for (int i = beg + t; i < end; i += 256)
        atomicAdd(&hist[(packed[i] >> 16) & 255], 1);
    __syncthreads();
    const int c = hist[t];
    for (int off = 1; off < 256; off <<= 1) {
        int u = (t >= off) ? hist[t - off] : 0;
        __syncthreads();
        hist[t] += u;
        __syncthreads();
    }
    const int excl = hist[t] - c;
    const int node = (b << 8) + t;
    if (node < N) {
        row_ptr[node] = beg + excl;
        invdeg[node] = 1.0f / fmaxf((float)c, 1.0f);
    }
    if (b == 0 && t == 0) row_ptr[N] = E;
    posq[t] = excl;
    __syncthreads();
    if (n <= FCAP) {
        for (int i = beg + t; i < end; i += 256) {
            unsigned pk = packed[i];
            int p = atomicAdd(&posq[(pk >> 16) & 255], 1);
            outq[p] = (ushort)(pk & 0xFFFFu);
        }
        __syncthreads();
        for (int i = t; i < n; i += 256) edge_csr[beg + i] = outq[i];
    } else {
        for (int i = beg + t; i < end; i += 256) {
            unsigned pk = packed[i];
            int p = atomicAdd(&posq[(pk >> 16) & 255], 1);
            edge_csr[beg + p] = (ushort)(pk & 0xFFFFu);
        }
    }
}

// ---------------- combined convert: W (bf16) + x (bf16 + fp8 shadow, zero-padded) -------------
__global__ void convert_all_kernel(const float* __restrict__ x,
                                   const float* __restrict__ Wl, const float* __restrict__ Wr,
                                   ushort* __restrict__ xb, unsigned* __restrict__ xq,
                                   ushort* __restrict__ Wb,
                                   int n4, int m4, int wtotal) {
    int gid = blockIdx.x * 256 + threadIdx.x;
    if (gid < wtotal) {
        int l = gid / (HH * 256);
        int rem = gid - l * (HH * 256);
        int col = rem >> 8;
        int k = rem & 255;
        float v = (k < HH) ? Wl[(size_t)l * HH * HH + col * HH + k]
                           : Wr[(size_t)l * HH * HH + col * HH + (k - HH)];
        Wb[gid] = (ushort)f2bf(v);
        return;
    }
    int idx = gid - wtotal;        // float4 units over MP*32
    if (idx >= m4) return;
    uint2 o = make_uint2(0u, 0u);
    unsigned q = 0u;
    if (idx < n4) {
        float4 v = ((const float4*)x)[idx];
        o.x = f2bf(v.x) | (f2bf(v.y) << 16);
        o.y = f2bf(v.z) | (f2bf(v.w) << 16);
        q = pack_fp8x4(v.x, v.y, v.z, v.w);
    }
    ((uint2*)xb)[idx] = o;
    xq[idx] = q;
}

// ---------------- gather (fp8 in, f32 accum, bf16 out), unroll-4 ----------------
__global__ __launch_bounds__(256) void gather_kernel(
    const unsigned* __restrict__ xq, const int* __restrict__ row_ptr,
    const ushort* __restrict__ edge_csr, const float* __restrict__ invdeg,
    ushort* __restrict__ aggb, int N)
{
    const int node = blockIdx.x * 16 + (threadIdx.x >> 4);
    const int l16 = threadIdx.x & 15;
    float a0=0,a1=0,a2=0,a3=0,a4=0,a5=0,a6=0,a7=0;
    float id = 0.f;
    if (node < N) {
        const int beg = row_ptr[node], end = row_ptr[node + 1];
        id = invdeg[node];
        int e = beg;
        for (; e + 3 < end; e += 4) {
            int s0 = edge_csr[e], s1 = edge_csr[e + 1];
            int s2 = edge_csr[e + 2], s3 = edge_csr[e + 3];
            uint2 v0 = *(const uint2*)(xq + (size_t)s0 * 32 + l16 * 2);
            uint2 v1 = *(const uint2*)(xq + (size_t)s1 * 32 + l16 * 2);
            uint2 v2 = *(const uint2*)(xq + (size_t)s2 * 32 + l16 * 2);
            uint2 v3 = *(const uint2*)(xq + (size_t)s3 * 32 + l16 * 2);
            f32x2 p;
            p = __builtin_amdgcn_cvt_pk_f32_fp8(v0.x, false); a0 += p.x; a1 += p.y;
            p = __builtin_amdgcn_cvt_pk_f32_fp8(v0.x, true);  a2 += p.x; a3 += p.y;
            p = __builtin_amdgcn_cvt_pk_f32_fp8(v0.y, false); a4 += p.x; a5 += p.y;
            p = __builtin_amdgcn_cvt_pk_f32_fp8(v0.y, true);  a6 += p.x; a7 += p.y;
            p = __builtin_amdgcn_cvt_pk_f32_fp8(v1.x, false); a0 += p.x; a1 += p.y;
            p = __builtin_amdgcn_cvt_pk_f32_fp8(v1.x, true);  a2 += p.x; a3 += p.y;
            p = __builtin_amdgcn_cvt_pk_f32_fp8(v1.y, false); a4 += p.x; a5 += p.y;
            p = __builtin_amdgcn_cvt_pk_f32_fp8(v1.y, true);  a6 += p.x; a7 += p.y;
            p = __builtin_amdgcn_cvt_pk_f32_fp8(v2.x, false); a0 += p.x; a1 += p.y;
            p = __builtin_amdgcn_cvt_pk_f32_fp8(v2.x, true);  a2 += p.x; a3 += p.y;
            p = __builtin_amdgcn_cvt_pk_f32_fp8(v2.y, false); a4 += p.x; a5 += p.y;
            p = __builtin_amdgcn_cvt_pk_f32_fp8(v2.y, true);  a6 += p.x; a7 += p.y;
            p = __builtin_amdgcn_cvt_pk_f32_fp8(v3.x, false); a0 += p.x; a1 += p.y;
            p = __builtin_amdgcn_cvt_pk_f32_fp8(v3.x, true);  a2 += p.x; a3 += p.y;
            p = __builtin_amdgcn_cvt_pk_f32_fp8(v3.y, false); a4 += p.x; a5 += p.y;
            p = __builtin_amdgcn_cvt_pk_f32_fp8(v3.y, true);  a6 += p.x; a7 += p.y;
        }
        for (; e < end; ++e) {
            int s0 = edge_csr[e];
            uint2 v0 = *(const uint2*)(xq + (size_t)s0 * 32 + l16 * 2);
            f32x2 p;
            p = __builtin_amdgcn_cvt_pk_f32_fp8(v0.x, false); a0 += p.x; a1 += p.y;
            p = __builtin_amdgcn_cvt_pk_f32_fp8(v0.x, true);  a2 += p.x; a3 += p.y;
            p = __builtin_amdgcn_cvt_pk_f32_fp8(v0.y, false); a4 += p.x; a5 += p.y;
            p = __builtin_amdgcn_cvt_pk_f32_fp8(v0.y, true);  a6 += p.x; a7 += p.y;
        }
    }
    uint4 o;
    o.x = f2bf(a0 * id) | (f2bf(a1 * id) << 16);
    o.y = f2bf(a2 * id) | (f2bf(a3 * id) << 16);
    o.z = f2bf(a4 * id) | (f2bf(a5 * id) << 16);
    o.w = f2bf(a6 * id) | (f2bf(a7 * id) << 16);
    *(uint4*)(aggb + (size_t)node * HH + l16 * 8) = o;
}

// ---------------- fused GEMM + BN + ReLU + residual (grid-barrier, h stays in regs) ---------
// 128-row x 128-col tile, 512 thr (8 waves, 16-col strip each), 64 KB dynamic LDS A-tile.
// 2 blocks/CU -> grid 391 <= 512 resident capacity -> all co-resident -> barrier safe.
__global__ __launch_bounds__(512) void fused_layer_kernel(
    const ushort* __restrict__ aggb, ushort* __restrict__ xb,
    const ushort* __restrict__ Wb, const float* __restrict__ bl,
    const float* __restrict__ gamma, const float* __restrict__ beta,
    float* __restrict__ stats, unsigned* __restrict__ bar,
    unsigned* __restrict__ xq, float* __restrict__ outf,
    float invN, int nblocks, int N, int residual, int final_layer)
{
    extern __shared__ ushort As[];          // 128 rows x 256 k bf16 = 64 KB; reused as C-tile
    __shared__ float s_sum[128];
    __shared__ float s_sum2[128];

    const int tid = threadIdx.x;
    const int lane = tid & 63;
    const int wave = tid >> 6;              // 0..7
    const int m0 = blockIdx.x * 128;
    const int l15 = lane & 15;
    const int lg = lane >> 4;
    const int col = wave * 16 + l15;        // this lane's output column

    // stage A: 4096 16B-chunks (XOR swizzle on global source, linear LDS dest)
#pragma unroll
    for (int i = 0; i < 8; ++i) {
        const int cb = (i * 8 + wave) * 64;          // wave-uniform chunk base
        const int L = cb + lane;
        const int r = L >> 5;                        // row 0..127
        const int c = L & 31;
        const int cs = (c & 0x18) | ((c & 7) ^ (r & 7));
        const ushort* gsrc = (cs < 16)
            ? (aggb + (size_t)(m0 + r) * HH + cs * 8)
            : (xb   + (size_t)(m0 + r) * HH + (cs - 16) * 8);
        gload_lds16(gsrc, &As[(size_t)cb * 8]);
    }

    // B preload: 8 k-steps for this wave's 16-col strip (32 VGPRs)
    bf16x8 bfr[8];
#pragma unroll
    for (int s = 0; s < 8; ++s)
        bfr[s] = *(const bf16x8*)(Wb + (size_t)col * 256 + s * 32 + lg * 8);

    if (tid < 128) { s_sum[tid] = 0.f; s_sum2[tid] = 0.f; }

    f32x4 acc[8];
#pragma unroll
    for (int rt = 0; rt < 8; ++rt) acc[rt] = (f32x4){0.f, 0.f, 0.f, 0.f};

    __syncthreads();   // drains vmcnt (global_load_lds); also publishes s_sum init

#pragma unroll
    for (int s = 0; s < 8; ++s) {
#pragma unroll
        for (int rt = 0; rt < 8; ++rt) {
            const int r = rt * 16 + l15;
            const int g = s * 4 + lg;
            const int c = (g & 0x18) | ((g & 7) ^ (r & 7));
            bf16x8 a = *(const bf16x8*)&As[r * 256 + c * 8];
            acc[rt] = __builtin_amdgcn_mfma_f32_16x16x32_bf16(a, bfr[s], acc[rt], 0, 0, 0);
        }
    }

    // stats (h = acc + bias, rows < N only)
    const float bias = bl[col];
    float s1 = 0.f, s2 = 0.f;
#pragma unroll
    for (int rt = 0; rt < 8; ++rt) {
#pragma unroll
        for (int r = 0; r < 4; ++r) {
            const int row = rt * 16 + lg * 4 + r;
            if (m0 + row < N) {
                float v = acc[rt][r] + bias;
                s1 += v; s2 += v * v;
            }
        }
    }
    atomicAdd(&s_sum[col], s1);
    atomicAdd(&s_sum2[col], s2);
    __syncthreads();
    if (tid < 128) {
        atomicAdd(&stats[tid], s_sum[tid]);
        atomicAdd(&stats[128 + tid], s_sum2[tid]);
    }
    // grid barrier
    if (tid == 0) {
        __threadfence();
        __hip_atomic_fetch_add(bar, 1u, __ATOMIC_ACQ_REL, __HIP_MEMORY_SCOPE_AGENT);
        while (__hip_atomic_load(bar, __ATOMIC_ACQUIRE, __HIP_MEMORY_SCOPE_AGENT) < (unsigned)nblocks)
            __builtin_amdgcn_s_sleep(8);
    }
    __syncthreads();

    // BN coefficients (atomic loads bypass stale per-XCD cache copies)
    const float sA = __hip_atomic_load(&stats[col], __ATOMIC_RELAXED, __HIP_MEMORY_SCOPE_AGENT);
    const float sB = __hip_atomic_load(&stats[128 + col], __ATOMIC_RELAXED, __HIP_MEMORY_SCOPE_AGENT);
    const float mean = sA * invN;
    const float var = sB * invN - mean * mean;
    const float aa = gamma[col] * rsqrtf(var + EPS);
    const float bb = beta[col] - mean * aa;

    // write relu(bn(h)) into LDS C-tile
    ushort* Cs = As;   // [128][136] ushort
#pragma unroll
    for (int rt = 0; rt < 8; ++rt) {
#pragma unroll
        for (int r = 0; r < 4; ++r) {
            const int row = rt * 16 + lg * 4 + r;
            float v = acc[rt][r] + bias;
            float o = fmaxf(fmaf(v, aa, bb), 0.f);
            Cs[row * 136 + col] = (ushort)f2bf(o);
        }
    }
    __syncthreads();

    // coalesced copy-out: + residual, write xb (bf16) + xq (fp8) or final f32 out
#pragma unroll
    for (int i = 0; i < 4; ++i) {
        const int ch = tid + i * 512;
        const int row = ch >> 4;
        const int q = ch & 15;
        const int grow = m0 + row;
        if (grow < N) {
            uint4 v = *(const uint4*)&Cs[row * 136 + q * 8];
            float o0 = bflo(v.x), o1 = bfhi(v.x);
            float o2 = bflo(v.y), o3 = bfhi(v.y);
            float o4 = bflo(v.z), o5 = bfhi(v.z);
            float o6 = bflo(v.w), o7 = bfhi(v.w);
            if (residual) {
                uint4 xw = *(const uint4*)(xb + (size_t)grow * HH + q * 8);
                o0 += bflo(xw.x); o1 += bfhi(xw.x);
                o2 += bflo(xw.y); o3 += bfhi(xw.y);
                o4 += bflo(xw.z); o5 += bfhi(xw.z);
                o6 += bflo(xw.w); o7 += bfhi(xw.w);
            }
            if (final_layer) {
                float* op = outf + (size_t)grow * HH + q * 8;
                *(float4*)op = make_float4(o0, o1, o2, o3);
                *(float4*)(op + 4) = make_float4(o4, o5, o6, o7);
            } else {
                uint4 ob;
                ob.x = f2bf(o0) | (f2bf(o1) << 16);
                ob.y = f2bf(o2) | (f2bf(o3) << 16);
                ob.z = f2bf(o4) | (f2bf(o5) << 16);
                ob.w = f2bf(o6) | (f2bf(o7) << 16);
                *(uint4*)(xb + (size_t)grow * HH + q * 8) = ob;
                uint2 qb;
                qb.x = pack_fp8x4(o0, o1, o2, o3);
                qb.y = pack_fp8x4(o4, o5, o6, o7);
                *(uint2*)(xq + (size_t)grow * 32 + q * 2) = qb;
            }
        }
    }
}

extern "C" void kernel_launch(void* const* d_in, const int* in_sizes, int n_in,
                              void* d_out, int out_size, void* d_ws, size_t ws_size,
                              hipStream_t stream) {
    const float* x     = (const float*)d_in[0];
    const int*   ei    = (const int*)d_in[1];
    const float* Wl    = (const float*)d_in[2];
    const float* bl    = (const float*)d_in[3];
    const float* Wr    = (const float*)d_in[4];
    const float* gamma = (const float*)d_in[5];
    const float* beta  = (const float*)d_in[6];
    float* out = (float*)d_out;

    const int N = in_sizes[0] / HH;           // 50000 (< 65536: ushort node ids)
    const int E = in_sizes[1] / 2;
    const int MP = ((N + 127) / 128) * 128;   // 128-row tiles
    const int NB = (N + 255) >> 8;
    const int* src = ei;
    const int* dst = ei + E;

    char* p = (char*)d_ws;
    ushort* aggb    = (ushort*)p; p += (size_t)MP * HH * 2;
    ushort* xb      = (ushort*)p; p += (size_t)MP * HH * 2;
    unsigned* xq    = (unsigned*)p; p += (size_t)MP * 32 * 4; // fp8 shadow of x (128 B/row)
    ushort* Wb      = (ushort*)p; p += (size_t)3 * HH * 256 * 2;
    float* invdeg   = (float*)p;  p += (size_t)N * 4;
    float* stats3   = (float*)p;  p += 768 * 4;
    unsigned* bar   = (unsigned*)p; p += 16 * 4;
    int* row_ptr    = (int*)p;    p += (size_t)(N + 4) * 4;
    int* bcnt       = (int*)p;    p += NBMAX * 4;
    int* boff       = (int*)p;    p += (NBMAX + 1) * 4;
    int* gpos       = (int*)p;    p += NBMAX * 4;
    unsigned* packed = (unsigned*)p; p += (size_t)E * 4;
    ushort* edge_csr = (ushort*)p;  p += (size_t)((E + 7) & ~7) * 2;

    // allow 64 KB dynamic LDS for the fused kernel
    hipFuncSetAttribute((const void*)fused_layer_kernel,
                        hipFuncAttributeMaxDynamicSharedMemorySize, 65536);

    // ---- CSR build (bucketed, once) ----
    zero_small_kernel<<<1, 256, 0, stream>>>(bcnt, stats3, bar);
    bucket_hist_kernel<<<512, 256, 0, stream>>>(dst, bcnt, E);
    bucket_scan_kernel<<<1, 256, 0, stream>>>(bcnt, boff, gpos, NB, E);
    bucket_scatter_kernel<<<256, 256, 0, stream>>>(src, dst, gpos, packed, E, 256);
    bucket_finalize_kernel<<<NB, 256, 0, stream>>>(packed, boff, row_ptr, invdeg, edge_csr, N, E);

    // ---- combined converts (once; zero-pads xb/xq to MP rows) ----
    const int wtotal = 3 * HH * 256;
    const int n4 = N * (HH / 4);
    const int m4 = MP * (HH / 4);
    convert_all_kernel<<<(wtotal + m4 + 255) / 256, 256, 0, stream>>>(
        x, Wl, Wr, xb, xq, Wb, n4, m4, wtotal);

    const int gather_blocks = MP / 16;
    const int fused_blocks = MP / 128;        // 391 <= 512 resident (2 blocks/CU) -> co-resident

    for (int layer = 0; layer < 3; ++layer) {
        gather_kernel<<<gather_blocks, 256, 0, stream>>>(
            xq, row_ptr, edge_csr, invdeg, aggb, N);

        fused_layer_kernel<<<fused_blocks, 512, 65536, stream>>>(
            aggb, xb, Wb + (size_t)layer * HH * 256, bl + (size_t)layer * HH,
            gamma + (size_t)layer * HH, beta + (size_t)layer * HH,
            stats3 + layer * 256, bar + 3 + layer,
            xq, out, 1.0f / (float)N, fused_blocks, N,
            layer > 0 ? 1 : 0, layer == 2 ? 1 : 0);
    }
}

// Round 15
// 211.676 us; speedup vs baseline: 1.3962x; 1.3103x over previous
//
#include <hip/hip_runtime.h>

#define HH 128
#define EPS 1e-5f
#define NBMAX 256     // max buckets (N < 65536 assumed: node ids fit ushort)
#define SCAP 40       // scatter LDS queue capacity per bucket
#define FCAP 12288    // finalize LDS edge capacity per bucket

typedef __bf16 bf16x8 __attribute__((ext_vector_type(8)));
typedef float f32x4 __attribute__((ext_vector_type(4)));
typedef float f32x2 __attribute__((ext_vector_type(2)));

__device__ __forceinline__ unsigned f2bf(float f) {
    unsigned u = __builtin_bit_cast(unsigned, f);
    return (u + 0x7FFFu + ((u >> 16) & 1u)) >> 16;   // RNE
}
__device__ __forceinline__ float bflo(unsigned w) { return __builtin_bit_cast(float, w << 16); }
__device__ __forceinline__ float bfhi(unsigned w) { return __builtin_bit_cast(float, w & 0xFFFF0000u); }

// pack 4 f32 -> 4 fp8 e4m3 (one uint); HW cvt (OCP on gfx950)
__device__ __forceinline__ unsigned pack_fp8x4(float f0, float f1, float f2, float f3) {
    unsigned r = 0;
    r = __builtin_amdgcn_cvt_pk_fp8_f32(f0, f1, r, false);   // bytes 0,1
    r = __builtin_amdgcn_cvt_pk_fp8_f32(f2, f3, r, true);    // bytes 2,3
    return r;
}

__device__ __forceinline__ void gload_lds16(const void* g, void* l) {
    __builtin_amdgcn_global_load_lds(
        (const __attribute__((address_space(1))) unsigned int*)g,
        (__attribute__((address_space(3))) unsigned int*)l,
        16, 0, 0);
}

// ---------------- tiny zero (bcnt + stats + barrier counters) ----------------
__global__ void zero_small_kernel(int* __restrict__ bcnt, float* __restrict__ stats3,
                                  unsigned* __restrict__ bar) {
    const int t = threadIdx.x;
    bcnt[t] = 0;
    stats3[t] = 0.f; stats3[256 + t] = 0.f; stats3[512 + t] = 0.f;
    if (t < 8) bar[t] = 0u;
}

// ---------------- CSR build (bucketed, once) ----------------
__global__ __launch_bounds__(256) void bucket_hist_kernel(const int* __restrict__ dst,
                                                          int* __restrict__ bcnt, int E) {
    __shared__ int h[NBMAX];
    const int t = threadIdx.x;
    h[t] = 0;
    __syncthreads();
    for (int e = blockIdx.x * 256 + t; e < E; e += gridDim.x * 256)
        atomicAdd(&h[dst[e] >> 8], 1);
    __syncthreads();
    if (h[t]) atomicAdd(&bcnt[t], h[t]);
}

__global__ __launch_bounds__(256) void bucket_scan_kernel(const int* __restrict__ bcnt,
                                                          int* __restrict__ boff,
                                                          int* __restrict__ gpos, int NB, int E) {
    __shared__ int s[NBMAX];
    const int t = threadIdx.x;
    s[t] = (t < NB) ? bcnt[t] : 0;
    __syncthreads();
    for (int off = 1; off < 256; off <<= 1) {
        int u = (t >= off) ? s[t - off] : 0;
        __syncthreads();
        s[t] += u;
        __syncthreads();
    }
    int excl = (t == 0) ? 0 : s[t - 1];
    if (t < NB) { boff[t] = excl; gpos[t] = excl; }
    if (t == 0) boff[NB] = E;
}

__global__ __launch_bounds__(256) void bucket_scatter_kernel(
    const int* __restrict__ src, const int* __restrict__ dst,
    int* __restrict__ gpos, unsigned* __restrict__ packed, int E, int GRID)
{
    __shared__ unsigned q[NBMAX][SCAP];
    __shared__ int qc[NBMAX];
    const int t = threadIdx.x;
    const int b = blockIdx.x;
    qc[t] = 0;
    __syncthreads();
    const int ebeg = (int)((long)b * E / GRID);
    const int eend = (int)((long)(b + 1) * E / GRID);
    for (int base = ebeg; base < eend; base += 256) {
        int e = base + t;
        if (e < eend) {
            int d = dst[e];
            unsigned pk = ((unsigned)d << 16) | (unsigned)src[e];
            int bk = d >> 8;
            int slot = atomicAdd(&qc[bk], 1);
            if (slot < SCAP) q[bk][slot] = pk;
            else { int p = atomicAdd(&gpos[bk], 1); packed[p] = pk; }
        }
        __syncthreads();
        int c = qc[t]; if (c > SCAP) c = SCAP;
        if (c >= 32) {
            int p = atomicAdd(&gpos[t], 32);
            for (int i = 0; i < 32; ++i) packed[p + i] = q[t][i];
            for (int i = 32; i < c; ++i) q[t][i - 32] = q[t][i];
            qc[t] = c - 32;
        } else {
            qc[t] = c;
        }
        __syncthreads();
    }
    int c = qc[t]; if (c > SCAP) c = SCAP;
    if (c > 0) {
        int p = atomicAdd(&gpos[t], c);
        for (int i = 0; i < c; ++i) packed[p + i] = q[t][i];
    }
}

__global__ __launch_bounds__(256) void bucket_finalize_kernel(
    const unsigned* __restrict__ packed, const int* __restrict__ boff,
    int* __restrict__ row_ptr, float* __restrict__ invdeg,
    ushort* __restrict__ edge_csr, int N, int E)
{
    __shared__ int hist[256];
    __shared__ int posq[256];
    __shared__ ushort outq[FCAP];
    const int b = blockIdx.x, t = threadIdx.x;
    const int beg = boff[b], end = boff[b + 1], n = end - beg;
    hist[t] = 0;
    __syncthreads();
    for (int i = beg + t; i < end; i += 256)
        atomicAdd(&hist[(packed[i] >> 16) & 255], 1);
    __syncthreads();
    const int c = hist[t];
    for (int off = 1; off < 256; off <<= 1) {
        int u = (t >= off) ? hist[t - off] : 0;
        __syncthreads();
        hist[t] += u;
        __syncthreads();
    }
    const int excl = hist[t] - c;
    const int node = (b << 8) + t;
    if (node < N) {
        row_ptr[node] = beg + excl;
        invdeg[node] = 1.0f / fmaxf((float)c, 1.0f);
    }
    if (b == 0 && t == 0) row_ptr[N] = E;
    posq[t] = excl;
    __syncthreads();
    if (n <= FCAP) {
        for (int i = beg + t; i < end; i += 256) {
            unsigned pk = packed[i];
            int p = atomicAdd(&posq[(pk >> 16) & 255], 1);
            outq[p] = (ushort)(pk & 0xFFFFu);
        }
        __syncthreads();
        for (int i = t; i < n; i += 256) edge_csr[beg + i] = outq[i];
    } else {
        for (int i = beg + t; i < end; i += 256) {
            unsigned pk = packed[i];
            int p = atomicAdd(&posq[(pk >> 16) & 255], 1);
            edge_csr[beg + p] = (ushort)(pk & 0xFFFFu);
        }
    }
}

// ---------------- combined convert: W (bf16) + x (bf16 + fp8 shadow, zero-padded) -------------
__global__ void convert_all_kernel(const float* __restrict__ x,
                                   const float* __restrict__ Wl, const float* __restrict__ Wr,
                                   ushort* __restrict__ xb, unsigned* __restrict__ xq,
                                   ushort* __restrict__ Wb,
                                   int n4, int m4, int wtotal) {
    int gid = blockIdx.x * 256 + threadIdx.x;
    if (gid < wtotal) {
        int l = gid / (HH * 256);
        int rem = gid - l * (HH * 256);
        int col = rem >> 8;
        int k = rem & 255;
        float v = (k < HH) ? Wl[(size_t)l * HH * HH + col * HH + k]
                           : Wr[(size_t)l * HH * HH + col * HH + (k - HH)];
        Wb[gid] = (ushort)f2bf(v);
        return;
    }
    int idx = gid - wtotal;        // float4 units over MP*32
    if (idx >= m4) return;
    uint2 o = make_uint2(0u, 0u);
    unsigned q = 0u;
    if (idx < n4) {
        float4 v = ((const float4*)x)[idx];
        o.x = f2bf(v.x) | (f2bf(v.y) << 16);
        o.y = f2bf(v.z) | (f2bf(v.w) << 16);
        q = pack_fp8x4(v.x, v.y, v.z, v.w);
    }
    ((uint2*)xb)[idx] = o;
    xq[idx] = q;
}

// ---------------- gather (fp8 in, f32 accum, bf16 out), unroll-4 ----------------
__global__ __launch_bounds__(256) void gather_kernel(
    const unsigned* __restrict__ xq, const int* __restrict__ row_ptr,
    const ushort* __restrict__ edge_csr, const float* __restrict__ invdeg,
    ushort* __restrict__ aggb, int N)
{
    const int node = blockIdx.x * 16 + (threadIdx.x >> 4);
    const int l16 = threadIdx.x & 15;
    float a0=0,a1=0,a2=0,a3=0,a4=0,a5=0,a6=0,a7=0;
    float id = 0.f;
    if (node < N) {
        const int beg = row_ptr[node], end = row_ptr[node + 1];
        id = invdeg[node];
        int e = beg;
        for (; e + 3 < end; e += 4) {
            int s0 = edge_csr[e], s1 = edge_csr[e + 1];
            int s2 = edge_csr[e + 2], s3 = edge_csr[e + 3];
            uint2 v0 = *(const uint2*)(xq + (size_t)s0 * 32 + l16 * 2);
            uint2 v1 = *(const uint2*)(xq + (size_t)s1 * 32 + l16 * 2);
            uint2 v2 = *(const uint2*)(xq + (size_t)s2 * 32 + l16 * 2);
            uint2 v3 = *(const uint2*)(xq + (size_t)s3 * 32 + l16 * 2);
            f32x2 p;
            p = __builtin_amdgcn_cvt_pk_f32_fp8(v0.x, false); a0 += p.x; a1 += p.y;
            p = __builtin_amdgcn_cvt_pk_f32_fp8(v0.x, true);  a2 += p.x; a3 += p.y;
            p = __builtin_amdgcn_cvt_pk_f32_fp8(v0.y, false); a4 += p.x; a5 += p.y;
            p = __builtin_amdgcn_cvt_pk_f32_fp8(v0.y, true);  a6 += p.x; a7 += p.y;
            p = __builtin_amdgcn_cvt_pk_f32_fp8(v1.x, false); a0 += p.x; a1 += p.y;
            p = __builtin_amdgcn_cvt_pk_f32_fp8(v1.x, true);  a2 += p.x; a3 += p.y;
            p = __builtin_amdgcn_cvt_pk_f32_fp8(v1.y, false); a4 += p.x; a5 += p.y;
            p = __builtin_amdgcn_cvt_pk_f32_fp8(v1.y, true);  a6 += p.x; a7 += p.y;
            p = __builtin_amdgcn_cvt_pk_f32_fp8(v2.x, false); a0 += p.x; a1 += p.y;
            p = __builtin_amdgcn_cvt_pk_f32_fp8(v2.x, true);  a2 += p.x; a3 += p.y;
            p = __builtin_amdgcn_cvt_pk_f32_fp8(v2.y, false); a4 += p.x; a5 += p.y;
            p = __builtin_amdgcn_cvt_pk_f32_fp8(v2.y, true);  a6 += p.x; a7 += p.y;
            p = __builtin_amdgcn_cvt_pk_f32_fp8(v3.x, false); a0 += p.x; a1 += p.y;
            p = __builtin_amdgcn_cvt_pk_f32_fp8(v3.x, true);  a2 += p.x; a3 += p.y;
            p = __builtin_amdgcn_cvt_pk_f32_fp8(v3.y, false); a4 += p.x; a5 += p.y;
            p = __builtin_amdgcn_cvt_pk_f32_fp8(v3.y, true);  a6 += p.x; a7 += p.y;
        }
        for (; e < end; ++e) {
            int s0 = edge_csr[e];
            uint2 v0 = *(const uint2*)(xq + (size_t)s0 * 32 + l16 * 2);
            f32x2 p;
            p = __builtin_amdgcn_cvt_pk_f32_fp8(v0.x, false); a0 += p.x; a1 += p.y;
            p = __builtin_amdgcn_cvt_pk_f32_fp8(v0.x, true);  a2 += p.x; a3 += p.y;
            p = __builtin_amdgcn_cvt_pk_f32_fp8(v0.y, false); a4 += p.x; a5 += p.y;
            p = __builtin_amdgcn_cvt_pk_f32_fp8(v0.y, true);  a6 += p.x; a7 += p.y;
        }
    }
    uint4 o;
    o.x = f2bf(a0 * id) | (f2bf(a1 * id) << 16);
    o.y = f2bf(a2 * id) | (f2bf(a3 * id) << 16);
    o.z = f2bf(a4 * id) | (f2bf(a5 * id) << 16);
    o.w = f2bf(a6 * id) | (f2bf(a7 * id) << 16);
    *(uint4*)(aggb + (size_t)node * HH + l16 * 8) = o;
}

// ---------------- fused GEMM + BN + ReLU + residual (grid-barrier, h stays in regs) ---------
// 256-row x 128-col tile, 512 thr (8 waves, 16-col strip each), 128 KB dynamic LDS A-tile.
// 1 block/CU (LDS-bound) and grid <= 256 -> all blocks co-resident -> manual barrier is safe.
// No __threadfence at the barrier: stats flow via device-scope atomics (coherent by
// themselves); the xb WAR is ordered by vmcnt-drain at __syncthreads before arrival.
__global__ __launch_bounds__(512) void fused_layer_kernel(
    const ushort* __restrict__ aggb, ushort* __restrict__ xb,
    const ushort* __restrict__ Wb, const float* __restrict__ bl,
    const float* __restrict__ gamma, const float* __restrict__ beta,
    float* __restrict__ stats, unsigned* __restrict__ bar,
    unsigned* __restrict__ xq, float* __restrict__ outf,
    float invN, int nblocks, int N, int residual, int final_layer)
{
    extern __shared__ ushort As[];          // 256 rows x 256 k bf16 = 128 KB; reused as C-tile
    __shared__ float s_sum[128];
    __shared__ float s_sum2[128];

    const int tid = threadIdx.x;
    const int lane = tid & 63;
    const int wave = tid >> 6;              // 0..7
    const int m0 = blockIdx.x * 256;
    const int l15 = lane & 15;
    const int lg = lane >> 4;
    const int col = wave * 16 + l15;        // this lane's output column

    // stage A: 8192 16B-chunks (XOR swizzle on global source, linear LDS dest)
#pragma unroll
    for (int i = 0; i < 16; ++i) {
        const int cb = (i * 8 + wave) * 64;          // wave-uniform chunk base
        const int L = cb + lane;
        const int r = L >> 5;                        // row 0..255
        const int c = L & 31;
        const int cs = (c & 0x18) | ((c & 7) ^ (r & 7));
        const ushort* gsrc = (cs < 16)
            ? (aggb + (size_t)(m0 + r) * HH + cs * 8)
            : (xb   + (size_t)(m0 + r) * HH + (cs - 16) * 8);
        gload_lds16(gsrc, &As[(size_t)cb * 8]);
    }

    // B preload: 8 k-steps for this wave's 16-col strip (32 VGPRs)
    bf16x8 bfr[8];
#pragma unroll
    for (int s = 0; s < 8; ++s)
        bfr[s] = *(const bf16x8*)(Wb + (size_t)col * 256 + s * 32 + lg * 8);

    if (tid < 128) { s_sum[tid] = 0.f; s_sum2[tid] = 0.f; }

    f32x4 acc[16];
#pragma unroll
    for (int rt = 0; rt < 16; ++rt) acc[rt] = (f32x4){0.f, 0.f, 0.f, 0.f};

    __syncthreads();   // drains vmcnt (global_load_lds); also publishes s_sum init

#pragma unroll
    for (int s = 0; s < 8; ++s) {
#pragma unroll
        for (int rt = 0; rt < 16; ++rt) {
            const int r = rt * 16 + l15;
            const int g = s * 4 + lg;
            const int c = (g & 0x18) | ((g & 7) ^ (r & 7));
            bf16x8 a = *(const bf16x8*)&As[r * 256 + c * 8];
            acc[rt] = __builtin_amdgcn_mfma_f32_16x16x32_bf16(a, bfr[s], acc[rt], 0, 0, 0);
        }
    }

    // stats (h = acc + bias, rows < N only)
    const float bias = bl[col];
    float s1 = 0.f, s2 = 0.f;
#pragma unroll
    for (int rt = 0; rt < 16; ++rt) {
#pragma unroll
        for (int r = 0; r < 4; ++r) {
            const int row = rt * 16 + lg * 4 + r;
            if (m0 + row < N) {
                float v = acc[rt][r] + bias;
                s1 += v; s2 += v * v;
            }
        }
    }
    atomicAdd(&s_sum[col], s1);
    atomicAdd(&s_sum2[col], s2);
    __syncthreads();
    if (tid < 128) {
        atomicAdd(&stats[tid], s_sum[tid]);       // device-scope, coherent point
        atomicAdd(&stats[128 + tid], s_sum2[tid]);
    }
    // grid barrier (arrival after syncthreads -> this block's atomics are complete)
    __syncthreads();
    if (tid == 0) {
        __hip_atomic_fetch_add(bar, 1u, __ATOMIC_ACQ_REL, __HIP_MEMORY_SCOPE_AGENT);
        while (__hip_atomic_load(bar, __ATOMIC_ACQUIRE, __HIP_MEMORY_SCOPE_AGENT) < (unsigned)nblocks)
            __builtin_amdgcn_s_sleep(8);
    }
    __syncthreads();

    // BN coefficients (atomic loads go to the coherent point; no stale L2 copies)
    const float sA = __hip_atomic_load(&stats[col], __ATOMIC_RELAXED, __HIP_MEMORY_SCOPE_AGENT);
    const float sB = __hip_atomic_load(&stats[128 + col], __ATOMIC_RELAXED, __HIP_MEMORY_SCOPE_AGENT);
    const float mean = sA * invN;
    const float var = sB * invN - mean * mean;
    const float aa = gamma[col] * rsqrtf(var + EPS);
    const float bb = beta[col] - mean * aa;

    // write relu(bn(h)) into LDS C-tile
    ushort* Cs = As;   // [256][136] ushort
#pragma unroll
    for (int rt = 0; rt < 16; ++rt) {
#pragma unroll
        for (int r = 0; r < 4; ++r) {
            const int row = rt * 16 + lg * 4 + r;
            float v = acc[rt][r] + bias;
            float o = fmaxf(fmaf(v, aa, bb), 0.f);
            Cs[row * 136 + col] = (ushort)f2bf(o);
        }
    }
    __syncthreads();

    // coalesced copy-out: + residual, write xb (bf16) + xq (fp8) or final f32 out
#pragma unroll
    for (int i = 0; i < 8; ++i) {
        const int ch = tid + i * 512;
        const int row = ch >> 4;
        const int q = ch & 15;
        const int grow = m0 + row;
        if (grow < N) {
            uint4 v = *(const uint4*)&Cs[row * 136 + q * 8];
            float o0 = bflo(v.x), o1 = bfhi(v.x);
            float o2 = bflo(v.y), o3 = bfhi(v.y);
            float o4 = bflo(v.z), o5 = bfhi(v.z);
            float o6 = bflo(v.w), o7 = bfhi(v.w);
            if (residual) {
                uint4 xw = *(const uint4*)(xb + (size_t)grow * HH + q * 8);
                o0 += bflo(xw.x); o1 += bfhi(xw.x);
                o2 += bflo(xw.y); o3 += bfhi(xw.y);
                o4 += bflo(xw.z); o5 += bfhi(xw.z);
                o6 += bflo(xw.w); o7 += bfhi(xw.w);
            }
            if (final_layer) {
                float* op = outf + (size_t)grow * HH + q * 8;
                *(float4*)op = make_float4(o0, o1, o2, o3);
                *(float4*)(op + 4) = make_float4(o4, o5, o6, o7);
            } else {
                uint4 ob;
                ob.x = f2bf(o0) | (f2bf(o1) << 16);
                ob.y = f2bf(o2) | (f2bf(o3) << 16);
                ob.z = f2bf(o4) | (f2bf(o5) << 16);
                ob.w = f2bf(o6) | (f2bf(o7) << 16);
                *(uint4*)(xb + (size_t)grow * HH + q * 8) = ob;
                uint2 qb;
                qb.x = pack_fp8x4(o0, o1, o2, o3);
                qb.y = pack_fp8x4(o4, o5, o6, o7);
                *(uint2*)(xq + (size_t)grow * 32 + q * 2) = qb;
            }
        }
    }
}

extern "C" void kernel_launch(void* const* d_in, const int* in_sizes, int n_in,
                              void* d_out, int out_size, void* d_ws, size_t ws_size,
                              hipStream_t stream) {
    const float* x     = (const float*)d_in[0];
    const int*   ei    = (const int*)d_in[1];
    const float* Wl    = (const float*)d_in[2];
    const float* bl    = (const float*)d_in[3];
    const float* Wr    = (const float*)d_in[4];
    const float* gamma = (const float*)d_in[5];
    const float* beta  = (const float*)d_in[6];
    float* out = (float*)d_out;

    const int N = in_sizes[0] / HH;           // 50000 (< 65536: ushort node ids)
    const int E = in_sizes[1] / 2;
    const int MP = ((N + 255) / 256) * 256;   // 256-row tiles
    const int NB = (N + 255) >> 8;
    const int* src = ei;
    const int* dst = ei + E;

    char* p = (char*)d_ws;
    ushort* aggb    = (ushort*)p; p += (size_t)MP * HH * 2;
    ushort* xb      = (ushort*)p; p += (size_t)MP * HH * 2;
    unsigned* xq    = (unsigned*)p; p += (size_t)MP * 32 * 4; // fp8 shadow of x (128 B/row)
    ushort* Wb      = (ushort*)p; p += (size_t)3 * HH * 256 * 2;
    float* invdeg   = (float*)p;  p += (size_t)N * 4;
    float* stats3   = (float*)p;  p += 768 * 4;
    unsigned* bar   = (unsigned*)p; p += 16 * 4;             // [3..5] layer barriers
    int* row_ptr    = (int*)p;    p += (size_t)(N + 4) * 4;
    int* bcnt       = (int*)p;    p += NBMAX * 4;
    int* boff       = (int*)p;    p += (NBMAX + 1) * 4;
    int* gpos       = (int*)p;    p += NBMAX * 4;
    unsigned* packed = (unsigned*)p; p += (size_t)E * 4;
    ushort* edge_csr = (ushort*)p;  p += (size_t)((E + 7) & ~7) * 2;

    // allow 128 KB dynamic LDS for the fused kernel (gfx950 LDS/CU = 160 KB)
    hipFuncSetAttribute((const void*)fused_layer_kernel,
                        hipFuncAttributeMaxDynamicSharedMemorySize, 131072);

    // ---- CSR build (bucketed, once) ----
    zero_small_kernel<<<1, 256, 0, stream>>>(bcnt, stats3, bar);
    bucket_hist_kernel<<<512, 256, 0, stream>>>(dst, bcnt, E);
    bucket_scan_kernel<<<1, 256, 0, stream>>>(bcnt, boff, gpos, NB, E);
    bucket_scatter_kernel<<<256, 256, 0, stream>>>(src, dst, gpos, packed, E, 256);
    bucket_finalize_kernel<<<NB, 256, 0, stream>>>(packed, boff, row_ptr, invdeg, edge_csr, N, E);

    // ---- combined converts (once; zero-pads xb/xq to MP rows) ----
    const int wtotal = 3 * HH * 256;
    const int n4 = N * (HH / 4);
    const int m4 = MP * (HH / 4);
    convert_all_kernel<<<(wtotal + m4 + 255) / 256, 256, 0, stream>>>(
        x, Wl, Wr, xb, xq, Wb, n4, m4, wtotal);

    const int gather_blocks = MP / 16;
    const int fused_blocks = MP / 256;        // 196 <= 256 -> co-resident (1 block/CU by LDS)

    for (int layer = 0; layer < 3; ++layer) {
        gather_kernel<<<gather_blocks, 256, 0, stream>>>(
            xq, row_ptr, edge_csr, invdeg, aggb, N);

        fused_layer_kernel<<<fused_blocks, 512, 131072, stream>>>(
            aggb, xb, Wb + (size_t)layer * HH * 256, bl + (size_t)layer * HH,
            gamma + (size_t)layer * HH, beta + (size_t)layer * HH,
            stats3 + layer * 256, bar + 3 + layer,
            xq, out, 1.0f / (float)N, fused_blocks, N,
            layer > 0 ? 1 : 0, layer == 2 ? 1 : 0);
    }
}